// Round 8
// baseline (637.258 us; speedup 1.0000x reference)
//
#include <hip/hip_runtime.h>
#include <math.h>

#define N_LOC 32768
#define CONTENT 512
#define ADDR_D 64
#define HID 1024
#define IN_D 256
#define OUT_D 10
#define OVERALL 576
#define GRU_IN 832
#define EPS_C 1e-7f
#define NSTEPS 8

__device__ __forceinline__ float wred(float v) {
    #pragma unroll
    for (int m = 32; m; m >>= 1) v += __shfl_xor(v, m, 64);
    return v;
}
__device__ __forceinline__ float sigm(float x) { return 1.0f / (1.0f + expf(-x)); }
__device__ __forceinline__ float dot4(float4 a, float4 b) {
    return a.x * b.x + a.y * b.y + a.z * b.z + a.w * b.w;
}

// ============================================================================
// FUSED COOPERATIVE PATH
// 256 blocks x 512 threads (1 block/CU = minimum occupancy -> co-residency safe).
// Memory matrix register-resident: 2048 waves x 16 rows, 128 floats/lane.
// ============================================================================
#define NB 256
#define NT 512
#define WPB 8
#define RPW 16                    // rows per wave
#define RCOLS (OVERALL + 1)       // 576 reading cols + ssum
#define NBAR 40
#define BAR_STRIDE (18 * 32)      // 16 group ctrs + 1 final + 1 flag, each on own 128B line
#define BARN (NBAR * BAR_STRIDE)

struct FP {
    const float *x, *h0, *mem, *addr;
    const float *W_q, *b_q, *u_s, *b_s, *u_l, *b_l;
    const float *W_e, *b_e, *W_ch, *W_ci, *b_c;
    const float *W_ih, *W_hh, *b_ih, *b_hh, *W_o, *b_o;
    float *part;     // [NSTEPS][RCOLS][NB]
    float *reading;  // [NSTEPS][OVERALL]
    float *query;    // [NSTEPS][OVERALL]
    float *erase;    // [NSTEPS][CONTENT]
    float *cand;     // [NSTEPS][CONTENT]
    float *H;        // [NSTEPS+1][HID]
    float *slots;    // [NSTEPS][8]: 1=us.h 2=ul.h
    float *ssum;     // [NSTEPS]
    int   *bar;
    float *out;
};

// two-level grid barrier: 16 groups x 16 blocks, padded counters (atomic line law:
// ~29ns per serialized RMW on a line -> 16+16 arrivals ~ 1us vs 7us flat).
__device__ __forceinline__ void gbar(int* __restrict__ bar, int idx) {
    __threadfence();
    __syncthreads();
    if (threadIdx.x == 0) {
        int* base = bar + idx * BAR_STRIDE;
        int g = (int)(blockIdx.x >> 4);
        int old = __hip_atomic_fetch_add(base + g * 32, 1, __ATOMIC_ACQ_REL,
                                         __HIP_MEMORY_SCOPE_AGENT);
        if (old == 15) {
            int o2 = __hip_atomic_fetch_add(base + 16 * 32, 1, __ATOMIC_ACQ_REL,
                                            __HIP_MEMORY_SCOPE_AGENT);
            if (o2 == 15)
                __hip_atomic_store(base + 17 * 32, 1, __ATOMIC_RELEASE,
                                   __HIP_MEMORY_SCOPE_AGENT);
        }
        while (__hip_atomic_load(base + 17 * 32, __ATOMIC_ACQUIRE,
                                 __HIP_MEMORY_SCOPE_AGENT) == 0)
            __builtin_amdgcn_s_sleep(8);
    }
    __syncthreads();
    __threadfence();
}

// small matvec tasks by global wave id; wave<->row pinning is stable across steps
// (persistent blocks) so each XCD's L2 keeps its weight slice hot.
// tq = step index for query/slots; erase/cand step = tq-1 (only when doEC).
__device__ void small_task(const FP& p, const float* __restrict__ h, int tq,
                           int gw, int lane, int doEC, const float* __restrict__ xS) {
    const float4* h4 = (const float4*)h;
    if (doEC && gw < CONTENT) {
        const float4* row = (const float4*)(p.W_e + (size_t)gw * HID);
        float d = 0.0f;
        #pragma unroll
        for (int i = 0; i < 4; i++) d += dot4(row[lane + 64 * i], h4[lane + 64 * i]);
        d = wred(d);
        if (lane == 0) p.erase[(tq - 1) * CONTENT + gw] = sigm(d + p.b_e[gw]);
    } else if (doEC && gw < 2 * CONTENT) {
        int r = gw - CONTENT;
        const float4* row = (const float4*)(p.W_ch + (size_t)r * HID);
        float d = 0.0f;
        #pragma unroll
        for (int i = 0; i < 4; i++) d += dot4(row[lane + 64 * i], h4[lane + 64 * i]);
        const float4* row2 = (const float4*)(p.W_ci + (size_t)r * IN_D);
        d += dot4(row2[lane], ((const float4*)xS)[lane]);
        d = wred(d);
        if (lane == 0) p.cand[(tq - 1) * CONTENT + r] = fmaxf(d + p.b_c[r], 0.0f);
    } else if (gw >= 1024 && gw < 1024 + OVERALL) {
        int r = gw - 1024;
        const float4* row = (const float4*)(p.W_q + (size_t)r * HID);
        float d = 0.0f;
        #pragma unroll
        for (int i = 0; i < 4; i++) d += dot4(row[lane + 64 * i], h4[lane + 64 * i]);
        d = wred(d);
        if (lane == 0) p.query[tq * OVERALL + r] = d + p.b_q[r];
    } else if (gw == 1024 + OVERALL) {
        const float4* us4 = (const float4*)p.u_s;
        float d = 0.0f;
        #pragma unroll
        for (int i = 0; i < 4; i++) d += dot4(us4[lane + 64 * i], h4[lane + 64 * i]);
        d = wred(d);
        if (lane == 0) p.slots[tq * 8 + 1] = d;
    } else if (gw == 1024 + OVERALL + 1) {
        const float4* ul4 = (const float4*)p.u_l;
        float d = 0.0f;
        #pragma unroll
        for (int i = 0; i < 4; i++) d += dot4(ul4[lane + 64 * i], h4[lane + 64 * i]);
        d = wred(d);
        if (lane == 0) p.slots[tq * 8 + 2] = d;
    }
}

__global__ void __launch_bounds__(NT, 2) k_fused(FP p) {
    const int tid = threadIdx.x, wid = tid >> 6, lane = tid & 63;
    const int b = blockIdx.x;
    const int gw = b * WPB + wid;
    const int wrow0 = wid * RPW;

    __shared__ __align__(16) float qecS[1600];
    __shared__ __align__(16) float lred[RCOLS];
    __shared__ float lsum8[WPB];
    __shared__ float asqS[128], emaS[128], expsS[128];
    __shared__ __align__(16) float xS[IN_D];
    __shared__ __align__(16) float hS[HID];
    __shared__ __align__(16) float rs[OVERALL];
    __shared__ float gp[4][8];
    __shared__ float lg[OUT_D];

    // ===== init: LDS state, x, H[0], mem -> registers =====
    if (tid < 128) emaS[tid] = 0.0f;
    for (int i = tid; i < IN_D; i += NT) xS[i] = p.x[i];
    if (b < 2) { int g = b * NT + tid; if (g < HID) p.H[g] = p.h0[g]; }

    float4 mA[RPW], mB[RPW];
    float ar[RPW];
    const size_t Rbase = (size_t)gw * RPW;
    #pragma unroll
    for (int r = 0; r < RPW; r++) {
        const float4* rp = (const float4*)(p.mem + (Rbase + r) * CONTENT);
        mA[r] = rp[lane];
        mB[r] = rp[64 + lane];
        float a = p.addr[(Rbase + r) * ADDR_D + lane];
        ar[r] = a;
        float sq = wred(a * a);
        if (lane == 0) asqS[wrow0 + r] = sq;
    }
    __syncthreads();   // xS ready for small_task cand path (unused at init, but cheap)
    small_task(p, p.h0, 0, gw, lane, 0, xS);   // query_0, us.h0, ul.h0
    gbar(p.bar, 0);

    #pragma unroll 1
    for (int t = 0; t < NSTEPS; t++) {
        // ---------------- phase 1: update + dots + sim + exp + partials ----------------
        const float* qg = p.query + t * OVERALL;
        for (int c = tid; c < OVERALL; c += NT) qecS[c] = qg[c];
        if (t > 0) {
            const float* eg = p.erase + (t - 1) * CONTENT;
            const float* cg = p.cand + (t - 1) * CONTENT;
            for (int c = tid; c < CONTENT; c += NT) {
                qecS[576 + c] = eg[c];
                qecS[1088 + c] = cg[c];
            }
        }
        for (int c = tid; c < RCOLS; c += NT) lred[c] = 0.0f;
        __syncthreads();

        const float4 q0 = *(const float4*)(qecS + 4 * lane);
        const float4 q1 = *(const float4*)(qecS + 256 + 4 * lane);
        const float qa = qecS[512 + lane];
        const float qq = wred(dot4(q0, q0) + dot4(q1, q1) + qa * qa);
        const float qnorm = sqrtf(qq);
        const float bs = p.slots[t * 8 + 1] + p.b_s[0];
        const float beta = (bs > 20.0f ? bs : log1pf(expf(bs))) + 1.0f;
        const float gamma = sigm(p.slots[t * 8 + 2] + p.b_l[0]);

        float4 e0 = {0,0,0,0}, e1 = {0,0,0,0}, c0 = {0,0,0,0}, c1 = {0,0,0,0};
        float invp = 0.0f;
        if (t > 0) {
            e0 = *(const float4*)(qecS + 576 + 4 * lane);
            e1 = *(const float4*)(qecS + 576 + 256 + 4 * lane);
            c0 = *(const float4*)(qecS + 1088 + 4 * lane);
            c1 = *(const float4*)(qecS + 1088 + 256 + 4 * lane);
            invp = 1.0f / p.ssum[t - 1];
        }

        float4 racc0 = {0,0,0,0}, racc1 = {0,0,0,0};
        float racca = 0.0f, lsum = 0.0f;
        #pragma unroll
        for (int r = 0; r < RPW; r++) {
            float eo = emaS[wrow0 + r];
            if (t > 0) {
                float wv = expsS[wrow0 + r] * invp;
                mA[r].x = mA[r].x * (1.0f - wv * e0.x) + wv * c0.x;
                mA[r].y = mA[r].y * (1.0f - wv * e0.y) + wv * c0.y;
                mA[r].z = mA[r].z * (1.0f - wv * e0.z) + wv * c0.z;
                mA[r].w = mA[r].w * (1.0f - wv * e0.w) + wv * c0.w;
                mB[r].x = mB[r].x * (1.0f - wv * e1.x) + wv * c1.x;
                mB[r].y = mB[r].y * (1.0f - wv * e1.y) + wv * c1.y;
                mB[r].z = mB[r].z * (1.0f - wv * e1.z) + wv * c1.z;
                mB[r].w = mB[r].w * (1.0f - wv * e1.w) + wv * c1.w;
            }
            float d = dot4(mA[r], q0) + dot4(mB[r], q1) + ar[r] * qa;
            float sq = dot4(mA[r], mA[r]) + dot4(mB[r], mB[r]);
            #pragma unroll
            for (int m = 32; m; m >>= 1) {
                d += __shfl_xor(d, m, 64);
                sq += __shfl_xor(sq, m, 64);
            }
            float sim = beta * d / (sqrtf(sq + asqS[wrow0 + r]) * qnorm + EPS_C);
            float es = expf(sim - gamma * eo);
            if (lane == 0) {
                emaS[wrow0 + r] = 0.1f * eo + 0.9f * sim;
                expsS[wrow0 + r] = es;
            }
            lsum += es;
            racc0.x += es * mA[r].x; racc0.y += es * mA[r].y;
            racc0.z += es * mA[r].z; racc0.w += es * mA[r].w;
            racc1.x += es * mB[r].x; racc1.y += es * mB[r].y;
            racc1.z += es * mB[r].z; racc1.w += es * mB[r].w;
            racca += es * ar[r];
        }
        atomicAdd(&lred[4 * lane + 0], racc0.x);
        atomicAdd(&lred[4 * lane + 1], racc0.y);
        atomicAdd(&lred[4 * lane + 2], racc0.z);
        atomicAdd(&lred[4 * lane + 3], racc0.w);
        atomicAdd(&lred[256 + 4 * lane + 0], racc1.x);
        atomicAdd(&lred[256 + 4 * lane + 1], racc1.y);
        atomicAdd(&lred[256 + 4 * lane + 2], racc1.z);
        atomicAdd(&lred[256 + 4 * lane + 3], racc1.w);
        atomicAdd(&lred[512 + lane], racca);
        if (lane == 0) lsum8[wid] = lsum;
        __syncthreads();
        float* pt = p.part + (size_t)t * RCOLS * NB;
        for (int c = tid; c < OVERALL; c += NT) pt[(size_t)c * NB + b] = lred[c];
        if (tid == 0) {
            float s = 0.0f;
            #pragma unroll
            for (int w = 0; w < WPB; w++) s += lsum8[w];
            pt[(size_t)OVERALL * NB + b] = s;
        }
        gbar(p.bar, 1 + t * 4);

        // ---------------- reduce partials: wave gw sums column gw ----------------
        if (gw < RCOLS) {
            const float4* p4 = (const float4*)(p.part + (size_t)t * RCOLS * NB
                                               + (size_t)gw * NB);
            float4 v = p4[lane];
            float acc = wred(v.x + v.y + v.z + v.w);
            if (lane == 0) {
                if (gw < OVERALL) p.reading[t * OVERALL + gw] = acc;
                else p.ssum[t] = acc;
            }
        }
        gbar(p.bar, 2 + t * 4);

        // ---------------- GRU: 4 units/block, gi-wave + gh-wave per unit ----------------
        {
            for (int c = tid; c < OVERALL; c += NT) rs[c] = p.reading[t * OVERALL + c];
            for (int c = tid; c < HID; c += NT) hS[c] = p.H[t * HID + c];
            __syncthreads();
            const float invs = 1.0f / p.ssum[t];
            const int u = wid >> 1, half = wid & 1;
            const int k = b * 4 + u;
            if (half == 0) {
                const float4* Wi0 = (const float4*)(p.W_ih + (size_t)k * GRU_IN);
                const float4* Wi1 = (const float4*)(p.W_ih + (size_t)(k + HID) * GRU_IN);
                const float4* Wi2 = (const float4*)(p.W_ih + (size_t)(k + 2 * HID) * GRU_IN);
                const float4* x4 = (const float4*)xS;
                const float4* r4 = (const float4*)rs;
                float gi0 = 0, gi1 = 0, gi2 = 0;
                {
                    float4 v = x4[lane];
                    gi0 += dot4(Wi0[lane], v);
                    gi1 += dot4(Wi1[lane], v);
                    gi2 += dot4(Wi2[lane], v);
                }
                #pragma unroll
                for (int i = 0; i < 2; i++) {
                    float4 v = r4[lane + 64 * i];
                    v.x *= invs; v.y *= invs; v.z *= invs; v.w *= invs;
                    gi0 += dot4(Wi0[64 + lane + 64 * i], v);
                    gi1 += dot4(Wi1[64 + lane + 64 * i], v);
                    gi2 += dot4(Wi2[64 + lane + 64 * i], v);
                }
                {
                    int j = 768 + lane;
                    float v = rs[512 + lane] * invs;
                    gi0 += p.W_ih[(size_t)k * GRU_IN + j] * v;
                    gi1 += p.W_ih[(size_t)(k + HID) * GRU_IN + j] * v;
                    gi2 += p.W_ih[(size_t)(k + 2 * HID) * GRU_IN + j] * v;
                }
                gi0 = wred(gi0); gi1 = wred(gi1); gi2 = wred(gi2);
                if (lane == 0) { gp[u][0] = gi0; gp[u][1] = gi1; gp[u][2] = gi2; }
            } else {
                const float4* Wh0 = (const float4*)(p.W_hh + (size_t)k * HID);
                const float4* Wh1 = (const float4*)(p.W_hh + (size_t)(k + HID) * HID);
                const float4* Wh2 = (const float4*)(p.W_hh + (size_t)(k + 2 * HID) * HID);
                const float4* h4 = (const float4*)hS;
                float gh0 = 0, gh1 = 0, gh2 = 0;
                #pragma unroll
                for (int i = 0; i < 4; i++) {
                    float4 v = h4[lane + 64 * i];
                    gh0 += dot4(Wh0[lane + 64 * i], v);
                    gh1 += dot4(Wh1[lane + 64 * i], v);
                    gh2 += dot4(Wh2[lane + 64 * i], v);
                }
                gh0 = wred(gh0); gh1 = wred(gh1); gh2 = wred(gh2);
                if (lane == 0) { gp[u][3] = gh0; gp[u][4] = gh1; gp[u][5] = gh2; }
            }
            __syncthreads();
            if (tid < 4) {
                int kk = b * 4 + tid;
                float rg = sigm(gp[tid][0] + p.b_ih[kk] + gp[tid][3] + p.b_hh[kk]);
                float z  = sigm(gp[tid][1] + p.b_ih[HID + kk] + gp[tid][4] + p.b_hh[HID + kk]);
                float n  = tanhf(gp[tid][2] + p.b_ih[2 * HID + kk]
                                 + rg * (gp[tid][5] + p.b_hh[2 * HID + kk]));
                p.H[(t + 1) * HID + kk] = (1.0f - z) * n + z * hS[kk];
            }
        }
        gbar(p.bar, 3 + t * 4);

        // ---------------- small matvecs for step t (erase/cand) + t+1 (query/slots) ----------------
        if (t < NSTEPS - 1) {
            small_task(p, p.H + (t + 1) * HID, t + 1, gw, lane, 1, xS);
            gbar(p.bar, 4 + t * 4);
        }
    }

    // ---------------- output (block 0) ----------------
    if (b == 0) {
        const float* h = p.H + NSTEPS * HID;
        for (int j = tid; j < HID; j += NT) p.out[j] = h[j];
        const float4* h4 = (const float4*)h;
        for (int u = wid; u < OUT_D; u += WPB) {
            const float4* row = (const float4*)(p.W_o + (size_t)u * HID);
            float d = 0.0f;
            #pragma unroll
            for (int i = 0; i < 4; i++) d += dot4(row[lane + 64 * i], h4[lane + 64 * i]);
            d = wred(d);
            if (lane == 0) lg[u] = d + p.b_o[u];
        }
        __syncthreads();
        if (tid == 0) {
            float m = -1e30f;
            for (int u = 0; u < OUT_D; u++) m = fmaxf(m, lg[u]);
            float se = 0.0f;
            for (int u = 0; u < OUT_D; u++) se += expf(lg[u] - m);
            float lse = m + logf(se);
            for (int u = 0; u < OUT_D; u++) p.out[HID + u] = lg[u] - lse;
        }
    }
}

__global__ __launch_bounds__(256) void k_zero(int* __restrict__ bar, int n) {
    int g = blockIdx.x * 256 + threadIdx.x;
    if (g < n) bar[g] = 0;
}

// ============================================================================
// FALLBACK PATH (round-7 structure, known-good 634us) — used only if the
// cooperative launch is unavailable/rejected.
// ============================================================================
#define NBLK_P 2048
#define NWAVE_P (NBLK_P * 4)

__global__ __launch_bounds__(256) void fb_init(const float* __restrict__ addrRows,
                                               float* __restrict__ addrsq,
                                               float* __restrict__ ema) {
    int tid = threadIdx.x, wid = tid >> 6, lane = tid & 63;
    int gid = blockIdx.x * 256 + tid;
    if (gid < N_LOC) ema[gid] = 0.0f;
    for (int i = blockIdx.x * 4 + wid; i < N_LOC; i += gridDim.x * 4) {
        float a = addrRows[(size_t)i * ADDR_D + lane];
        float sq = wred(a * a);
        if (lane == 0) addrsq[i] = sq;
    }
}

__global__ __launch_bounds__(256) void fb_small(
    const float* __restrict__ W_e, const float* __restrict__ b_e,
    const float* __restrict__ W_ch, const float* __restrict__ W_ci, const float* __restrict__ b_c,
    const float* __restrict__ W_q, const float* __restrict__ b_q,
    const float* __restrict__ u_s, const float* __restrict__ u_l,
    const float* __restrict__ x, const float* __restrict__ h,
    float* __restrict__ erase, float* __restrict__ cand, float* __restrict__ query,
    float* __restrict__ slots_t, int doEC) {
    int tid = threadIdx.x, wid = tid >> 6, lane = tid & 63;
    int t = blockIdx.x * 4 + wid;
    const int base = doEC ? 2 * CONTENT : 0;
    const float4* h4 = (const float4*)h;
    const float4* x4 = (const float4*)x;
    if (doEC && t < CONTENT) {
        const float4* row = (const float4*)(W_e + (size_t)t * HID);
        float d = 0.0f;
        #pragma unroll
        for (int i = 0; i < 4; i++) d += dot4(row[lane + 64 * i], h4[lane + 64 * i]);
        d = wred(d);
        if (lane == 0) erase[t] = sigm(d + b_e[t]);
    } else if (doEC && t < 2 * CONTENT) {
        int r = t - CONTENT;
        const float4* row = (const float4*)(W_ch + (size_t)r * HID);
        float d = 0.0f;
        #pragma unroll
        for (int i = 0; i < 4; i++) d += dot4(row[lane + 64 * i], h4[lane + 64 * i]);
        const float4* row2 = (const float4*)(W_ci + (size_t)r * IN_D);
        d += dot4(row2[lane], x4[lane]);
        d = wred(d);
        if (lane == 0) cand[r] = fmaxf(d + b_c[r], 0.0f);
    } else if (t >= base && t < base + OVERALL) {
        int r = t - base;
        const float4* row = (const float4*)(W_q + (size_t)r * HID);
        float d = 0.0f;
        #pragma unroll
        for (int i = 0; i < 4; i++) d += dot4(row[lane + 64 * i], h4[lane + 64 * i]);
        d = wred(d);
        if (lane == 0) query[r] = d + b_q[r];
    } else if (t == base + OVERALL) {
        const float4* us4 = (const float4*)u_s;
        float d = 0.0f;
        #pragma unroll
        for (int i = 0; i < 4; i++) d += dot4(us4[lane + 64 * i], h4[lane + 64 * i]);
        d = wred(d);
        if (lane == 0) slots_t[1] = d;
    } else if (t == base + OVERALL + 1) {
        const float4* ul4 = (const float4*)u_l;
        float d = 0.0f;
        #pragma unroll
        for (int i = 0; i < 4; i++) d += dot4(ul4[lane + 64 * i], h4[lane + 64 * i]);
        d = wred(d);
        if (lane == 0) slots_t[2] = d;
    }
}

__global__ __launch_bounds__(256) void fb_passAB(
    const float* __restrict__ memIn, float* __restrict__ memOut,
    int doUpdate, int doStore,
    const float* __restrict__ addrRows, const float* __restrict__ query,
    const float* __restrict__ erase, const float* __restrict__ cand,
    const float* __restrict__ addrsq, float* __restrict__ ema,
    float* __restrict__ exp_s, float* __restrict__ part,
    const float* __restrict__ slots_t, const float* __restrict__ ssum_prev,
    const float* __restrict__ b_sh, const float* __restrict__ b_lr) {
    int tid = threadIdx.x, wid = tid >> 6, lane = tid & 63;
    int gw = blockIdx.x * 4 + wid;

    __shared__ float lred[OVERALL];
    __shared__ float lsum4[4];
    for (int c = tid; c < OVERALL; c += 256) lred[c] = 0.0f;

    const float4 q0 = *(const float4*)(query + 4 * lane);
    const float4 q1 = *(const float4*)(query + 256 + 4 * lane);
    const float qa = query[512 + lane];
    const float qq = wred(dot4(q0, q0) + dot4(q1, q1) + qa * qa);
    const float qnorm = sqrtf(qq);
    const float bs = slots_t[1] + b_sh[0];
    const float beta = (bs > 20.0f ? bs : log1pf(expf(bs))) + 1.0f;
    const float gamma = sigm(slots_t[2] + b_lr[0]);

    float4 e0 = {0,0,0,0}, e1 = {0,0,0,0}, c0 = {0,0,0,0}, c1 = {0,0,0,0};
    float invp = 0.0f;
    if (doUpdate) {
        e0 = *(const float4*)(erase + 4 * lane);
        e1 = *(const float4*)(erase + 256 + 4 * lane);
        c0 = *(const float4*)(cand + 4 * lane);
        c1 = *(const float4*)(cand + 256 + 4 * lane);
        invp = 1.0f / ssum_prev[0];
    }
    __syncthreads();

    float4 racc0 = {0,0,0,0}, racc1 = {0,0,0,0};
    float racca = 0.0f, lsum = 0.0f;

    #pragma unroll
    for (int it = 0; it < 2; it++) {
        const int i0 = gw + it * (2 * NWAVE_P);
        const int i1 = i0 + NWAVE_P;
        const float4* r0p = (const float4*)(memIn + (size_t)i0 * CONTENT);
        const float4* r1p = (const float4*)(memIn + (size_t)i1 * CONTENT);
        float4 m00 = r0p[lane];
        float4 m01 = r0p[64 + lane];
        float4 m10 = r1p[lane];
        float4 m11 = r1p[64 + lane];
        float av0 = addrRows[(size_t)i0 * ADDR_D + lane];
        float av1 = addrRows[(size_t)i1 * ADDR_D + lane];
        float eo0 = ema[i0], eo1 = ema[i1];
        float asq0 = addrsq[i0], asq1 = addrsq[i1];

        if (doUpdate) {
            float wv0 = exp_s[i0] * invp;
            float wv1 = exp_s[i1] * invp;
            m00.x = m00.x * (1.0f - wv0 * e0.x) + wv0 * c0.x;
            m00.y = m00.y * (1.0f - wv0 * e0.y) + wv0 * c0.y;
            m00.z = m00.z * (1.0f - wv0 * e0.z) + wv0 * c0.z;
            m00.w = m00.w * (1.0f - wv0 * e0.w) + wv0 * c0.w;
            m01.x = m01.x * (1.0f - wv0 * e1.x) + wv0 * c1.x;
            m01.y = m01.y * (1.0f - wv0 * e1.y) + wv0 * c1.y;
            m01.z = m01.z * (1.0f - wv0 * e1.z) + wv0 * c1.z;
            m01.w = m01.w * (1.0f - wv0 * e1.w) + wv0 * c1.w;
            m10.x = m10.x * (1.0f - wv1 * e0.x) + wv1 * c0.x;
            m10.y = m10.y * (1.0f - wv1 * e0.y) + wv1 * c0.y;
            m10.z = m10.z * (1.0f - wv1 * e0.z) + wv1 * c0.z;
            m10.w = m10.w * (1.0f - wv1 * e0.w) + wv1 * c0.w;
            m11.x = m11.x * (1.0f - wv1 * e1.x) + wv1 * c1.x;
            m11.y = m11.y * (1.0f - wv1 * e1.y) + wv1 * c1.y;
            m11.z = m11.z * (1.0f - wv1 * e1.z) + wv1 * c1.z;
            m11.w = m11.w * (1.0f - wv1 * e1.w) + wv1 * c1.w;
            if (doStore) {
                float4* o0 = (float4*)(memOut + (size_t)i0 * CONTENT);
                float4* o1 = (float4*)(memOut + (size_t)i1 * CONTENT);
                o0[lane] = m00;
                o0[64 + lane] = m01;
                o1[lane] = m10;
                o1[64 + lane] = m11;
            }
        }

        float d0 = dot4(m00, q0) + dot4(m01, q1) + av0 * qa;
        float d1 = dot4(m10, q0) + dot4(m11, q1) + av1 * qa;
        float s0 = dot4(m00, m00) + dot4(m01, m01);
        float s1 = dot4(m10, m10) + dot4(m11, m11);
        #pragma unroll
        for (int m = 32; m; m >>= 1) {
            d0 += __shfl_xor(d0, m, 64);
            s0 += __shfl_xor(s0, m, 64);
            d1 += __shfl_xor(d1, m, 64);
            s1 += __shfl_xor(s1, m, 64);
        }
        float sim0 = beta * d0 / (sqrtf(s0 + asq0) * qnorm + EPS_C);
        float sim1 = beta * d1 / (sqrtf(s1 + asq1) * qnorm + EPS_C);
        float es0 = expf(sim0 - gamma * eo0);
        float es1 = expf(sim1 - gamma * eo1);
        if (lane == 0) {
            ema[i0] = 0.1f * eo0 + 0.9f * sim0;
            ema[i1] = 0.1f * eo1 + 0.9f * sim1;
            exp_s[i0] = es0;
            exp_s[i1] = es1;
        }
        lsum += es0 + es1;
        racc0.x += es0 * m00.x + es1 * m10.x;
        racc0.y += es0 * m00.y + es1 * m10.y;
        racc0.z += es0 * m00.z + es1 * m10.z;
        racc0.w += es0 * m00.w + es1 * m10.w;
        racc1.x += es0 * m01.x + es1 * m11.x;
        racc1.y += es0 * m01.y + es1 * m11.y;
        racc1.z += es0 * m01.z + es1 * m11.z;
        racc1.w += es0 * m01.w + es1 * m11.w;
        racca += es0 * av0 + es1 * av1;
    }

    atomicAdd(&lred[4 * lane + 0], racc0.x);
    atomicAdd(&lred[4 * lane + 1], racc0.y);
    atomicAdd(&lred[4 * lane + 2], racc0.z);
    atomicAdd(&lred[4 * lane + 3], racc0.w);
    atomicAdd(&lred[256 + 4 * lane + 0], racc1.x);
    atomicAdd(&lred[256 + 4 * lane + 1], racc1.y);
    atomicAdd(&lred[256 + 4 * lane + 2], racc1.z);
    atomicAdd(&lred[256 + 4 * lane + 3], racc1.w);
    atomicAdd(&lred[512 + lane], racca);
    if (lane == 0) lsum4[wid] = lsum;
    __syncthreads();

    const int b = blockIdx.x;
    for (int c = tid; c < OVERALL; c += 256)
        part[(size_t)c * NBLK_P + b] = lred[c];
    if (tid == 0)
        part[(size_t)OVERALL * NBLK_P + b] = lsum4[0] + lsum4[1] + lsum4[2] + lsum4[3];
}

__global__ __launch_bounds__(256) void fb_red(const float* __restrict__ part,
                                              float* __restrict__ reading_t,
                                              float* __restrict__ ssum_t) {
    int tid = threadIdx.x, wid = tid >> 6, lane = tid & 63;
    int w = blockIdx.x * 4 + wid;
    if (w >= RCOLS) return;
    const float4* p4 = (const float4*)(part + (size_t)w * NBLK_P);
    float acc = 0.0f;
    #pragma unroll
    for (int i = 0; i < NBLK_P / 4 / 64; i++) {
        float4 v = p4[lane + 64 * i];
        acc += v.x + v.y + v.z + v.w;
    }
    acc = wred(acc);
    if (lane == 0) {
        if (w < OVERALL) reading_t[w] = acc;
        else ssum_t[0] = acc;
    }
}

__global__ __launch_bounds__(256) void fb_gru(
    const float* __restrict__ W_ih, const float* __restrict__ W_hh,
    const float* __restrict__ b_ih, const float* __restrict__ b_hh,
    const float* __restrict__ x, const float* __restrict__ reading_t,
    const float* __restrict__ ssum_t,
    const float* __restrict__ hcur, float* __restrict__ hnew) {
    int tid = threadIdx.x, wid = tid >> 6, lane = tid & 63;
    __shared__ __align__(16) float rsl[OVERALL];
    for (int c = tid; c < OVERALL; c += 256) rsl[c] = reading_t[c];
    __syncthreads();

    const int k = blockIdx.x * 4 + wid;
    if (k >= HID) return;
    const float invs = 1.0f / ssum_t[0];
    const float4* x4 = (const float4*)x;
    const float4* r4 = (const float4*)rsl;
    const float4* h4 = (const float4*)hcur;
    const float4* Wi0 = (const float4*)(W_ih + (size_t)k * GRU_IN);
    const float4* Wi1 = (const float4*)(W_ih + (size_t)(k + HID) * GRU_IN);
    const float4* Wi2 = (const float4*)(W_ih + (size_t)(k + 2 * HID) * GRU_IN);
    float gi0 = 0, gi1 = 0, gi2 = 0;
    {
        float4 v = x4[lane];
        gi0 += dot4(Wi0[lane], v); gi1 += dot4(Wi1[lane], v); gi2 += dot4(Wi2[lane], v);
    }
    #pragma unroll
    for (int i = 0; i < 2; i++) {
        float4 v = r4[lane + 64 * i];
        v.x *= invs; v.y *= invs; v.z *= invs; v.w *= invs;
        gi0 += dot4(Wi0[64 + lane + 64 * i], v);
        gi1 += dot4(Wi1[64 + lane + 64 * i], v);
        gi2 += dot4(Wi2[64 + lane + 64 * i], v);
    }
    {
        int j = 768 + lane;
        float v = rsl[512 + lane] * invs;
        gi0 += W_ih[(size_t)k * GRU_IN + j] * v;
        gi1 += W_ih[(size_t)(k + HID) * GRU_IN + j] * v;
        gi2 += W_ih[(size_t)(k + 2 * HID) * GRU_IN + j] * v;
    }
    const float4* Wh0 = (const float4*)(W_hh + (size_t)k * HID);
    const float4* Wh1 = (const float4*)(W_hh + (size_t)(k + HID) * HID);
    const float4* Wh2 = (const float4*)(W_hh + (size_t)(k + 2 * HID) * HID);
    float gh0 = 0, gh1 = 0, gh2 = 0;
    #pragma unroll
    for (int i = 0; i < 4; i++) {
        float4 v = h4[lane + 64 * i];
        gh0 += dot4(Wh0[lane + 64 * i], v);
        gh1 += dot4(Wh1[lane + 64 * i], v);
        gh2 += dot4(Wh2[lane + 64 * i], v);
    }
    gi0 = wred(gi0); gi1 = wred(gi1); gi2 = wred(gi2);
    gh0 = wred(gh0); gh1 = wred(gh1); gh2 = wred(gh2);
    if (lane == 0) {
        float r = sigm(gi0 + b_ih[k] + gh0 + b_hh[k]);
        float z = sigm(gi1 + b_ih[HID + k] + gh1 + b_hh[HID + k]);
        float n = tanhf(gi2 + b_ih[2 * HID + k] + r * (gh2 + b_hh[2 * HID + k]));
        hnew[k] = (1.0f - z) * n + z * hcur[k];
    }
}

__global__ __launch_bounds__(256) void fb_out(const float* __restrict__ W_o,
                                              const float* __restrict__ b_o,
                                              const float* __restrict__ h,
                                              float* __restrict__ out) {
    int tid = threadIdx.x, wid = tid >> 6, lane = tid & 63;
    __shared__ float lg[OUT_D];
    for (int j = tid; j < HID; j += 256) out[j] = h[j];
    const float4* h4 = (const float4*)h;
    for (int u = wid; u < OUT_D; u += 4) {
        const float4* row = (const float4*)(W_o + (size_t)u * HID);
        float d = 0.0f;
        #pragma unroll
        for (int i = 0; i < 4; i++) d += dot4(row[lane + 64 * i], h4[lane + 64 * i]);
        d = wred(d);
        if (lane == 0) lg[u] = d + b_o[u];
    }
    __syncthreads();
    if (tid == 0) {
        float m = -1e30f;
        for (int u = 0; u < OUT_D; u++) m = fmaxf(m, lg[u]);
        float se = 0.0f;
        for (int u = 0; u < OUT_D; u++) se += expf(lg[u] - m);
        float lse = m + logf(se);
        for (int u = 0; u < OUT_D; u++) out[HID + u] = lg[u] - lse;
    }
}

extern "C" void kernel_launch(void* const* d_in, const int* in_sizes, int n_in,
                              void* d_out, int out_size, void* d_ws, size_t ws_size,
                              hipStream_t stream) {
    const float* x    = (const float*)d_in[0];
    const float* h0   = (const float*)d_in[1];
    const float* memC = (const float*)d_in[2];
    const float* addrR= (const float*)d_in[3];
    const float* W_q  = (const float*)d_in[4];
    const float* b_q  = (const float*)d_in[5];
    const float* u_s  = (const float*)d_in[6];
    const float* b_s  = (const float*)d_in[7];
    const float* u_l  = (const float*)d_in[8];
    const float* b_l  = (const float*)d_in[9];
    const float* W_e  = (const float*)d_in[10];
    const float* b_e  = (const float*)d_in[11];
    const float* W_ch = (const float*)d_in[12];
    const float* W_ci = (const float*)d_in[13];
    const float* b_c  = (const float*)d_in[14];
    const float* W_ih = (const float*)d_in[15];
    const float* W_hh = (const float*)d_in[16];
    const float* b_ih = (const float*)d_in[17];
    const float* b_hh = (const float*)d_in[18];
    const float* W_o  = (const float*)d_in[19];
    const float* b_o  = (const float*)d_in[20];

    float* wsF = (float*)d_ws;

    // ---------- fused-path ws layout (overlaps fallback layout; only one path runs) ----------
    size_t off = 0;
    float* f_part    = wsF + off; off += (size_t)NSTEPS * RCOLS * NB;
    float* f_reading = wsF + off; off += NSTEPS * OVERALL;
    float* f_query   = wsF + off; off += NSTEPS * OVERALL;
    float* f_erase   = wsF + off; off += NSTEPS * CONTENT;
    float* f_cand    = wsF + off; off += NSTEPS * CONTENT;
    float* f_H       = wsF + off; off += (NSTEPS + 1) * HID;
    float* f_slots   = wsF + off; off += NSTEPS * 8;
    float* f_ssum    = wsF + off; off += 16;
    int*   f_bar     = (int*)(wsF + off); off += BARN;
    size_t fusedFloats = off;

    bool coop = ws_size >= fusedFloats * sizeof(float);
    if (coop) {
        int nbk = 0;
        hipError_t oe = hipOccupancyMaxActiveBlocksPerMultiprocessor(
            &nbk, (const void*)k_fused, NT, 0);
        coop = (oe == hipSuccess && nbk >= 1);
    }
    if (coop) {
        k_zero<<<(BARN + 255) / 256, 256, 0, stream>>>(f_bar, BARN);
        FP p;
        p.x = x; p.h0 = h0; p.mem = memC; p.addr = addrR;
        p.W_q = W_q; p.b_q = b_q; p.u_s = u_s; p.b_s = b_s; p.u_l = u_l; p.b_l = b_l;
        p.W_e = W_e; p.b_e = b_e; p.W_ch = W_ch; p.W_ci = W_ci; p.b_c = b_c;
        p.W_ih = W_ih; p.W_hh = W_hh; p.b_ih = b_ih; p.b_hh = b_hh;
        p.W_o = W_o; p.b_o = b_o;
        p.part = f_part; p.reading = f_reading; p.query = f_query;
        p.erase = f_erase; p.cand = f_cand; p.H = f_H; p.slots = f_slots;
        p.ssum = f_ssum; p.bar = f_bar; p.out = (float*)d_out;
        void* args[] = { (void*)&p };
        coop = (hipLaunchCooperativeKernel((const void*)k_fused, dim3(NB), dim3(NT),
                                           args, 0, stream) == hipSuccess);
    }
    if (coop) return;

    // ---------- fallback: round-7 multi-kernel path ----------
    const size_t MEMF = (size_t)N_LOC * CONTENT;
    const size_t SM_ADDRSQ = 0;
    const size_t SM_EXPS   = SM_ADDRSQ + N_LOC;
    const size_t SM_EMA    = SM_EXPS + N_LOC;
    const size_t SM_QUERY  = SM_EMA + N_LOC;
    const size_t SM_ER     = SM_QUERY + NSTEPS * OVERALL;
    const size_t SM_CAND   = SM_ER + NSTEPS * CONTENT;
    const size_t SM_H      = SM_CAND + NSTEPS * CONTENT;
    const size_t SM_SLOTS  = SM_H + (NSTEPS + 1) * HID;
    const size_t SM_SSUMR  = SM_SLOTS + NSTEPS * 8;
    const size_t SM_READ   = SM_SSUMR + 16;
    const size_t SM_PART   = SM_READ + NSTEPS * OVERALL;
    const size_t SM_TOT    = SM_PART + (size_t)RCOLS * NBLK_P;

    bool useWs = ws_size >= (MEMF + SM_TOT) * sizeof(float);
    float* memBuf = useWs ? wsF : (float*)d_in[2];
    float* sb     = useWs ? (wsF + MEMF) : wsF;

    float* addrsq  = sb + SM_ADDRSQ;
    float* exp_s   = sb + SM_EXPS;
    float* ema     = sb + SM_EMA;
    float* query   = sb + SM_QUERY;
    float* erase   = sb + SM_ER;
    float* cand    = sb + SM_CAND;
    float* H       = sb + SM_H;
    float* slots   = sb + SM_SLOTS;
    float* ssum_red= sb + SM_SSUMR;
    float* reading = sb + SM_READ;
    float* part    = sb + SM_PART;

    fb_init<<<512, 256, 0, stream>>>(addrR, addrsq, ema);
    fb_small<<<(OVERALL + 2 + 3) / 4, 256, 0, stream>>>(
        W_e, b_e, W_ch, W_ci, b_c, W_q, b_q, u_s, u_l, x, h0,
        erase, cand, query, slots, 0);

    const float* hcur = h0;
    for (int t = 0; t < NSTEPS; t++) {
        float* slt = slots + t * 8;
        int doUpd = (t > 0) ? 1 : 0;
        int doStore = (t >= 1 && t <= NSTEPS - 2) ? 1 : 0;
        const float* memIn = (useWs && t <= 1) ? memC : memBuf;
        fb_passAB<<<NBLK_P, 256, 0, stream>>>(
            memIn, memBuf, doUpd, doStore, addrR,
            query + t * OVERALL,
            erase + (t > 0 ? (t - 1) : 0) * CONTENT,
            cand + (t > 0 ? (t - 1) : 0) * CONTENT,
            addrsq, ema, exp_s, part,
            slt, (t > 0 ? ssum_red + (t - 1) : ssum_red), b_s, b_l);
        fb_red<<<(RCOLS + 3) / 4, 256, 0, stream>>>(part, reading + t * OVERALL,
                                                   ssum_red + t);
        float* hn = H + (t + 1) * HID;
        fb_gru<<<HID / 4, 256, 0, stream>>>(W_ih, W_hh, b_ih, b_hh, x,
                                            reading + t * OVERALL, ssum_red + t,
                                            hcur, hn);
        if (t < NSTEPS - 1) {
            fb_small<<<(2 * CONTENT + OVERALL + 2 + 3) / 4, 256, 0, stream>>>(
                W_e, b_e, W_ch, W_ci, b_c, W_q, b_q, u_s, u_l, x, hn,
                erase + t * CONTENT, cand + t * CONTENT,
                query + (t + 1) * OVERALL, slots + (t + 1) * 8, 1);
        }
        hcur = hn;
    }
    fb_out<<<1, 256, 0, stream>>>(W_o, b_o, hcur, (float*)d_out);
}